// Round 1
// baseline (785.649 us; speedup 1.0000x reference)
//
#include <hip/hip_runtime.h>

// SLAYER SNN forward, round 16 = round 15 with conv restructure:
//  - z=1 conv grids, NCO doubled (L1 3->6, L3 6->12, L5 12->24): halves the
//    per-FMA activation ds_read + LDS staging cost (input tile staged once,
//    each window read once for all CO handled by the wave).
//  - weights relaid per co-group contiguous: Wg[g][ci][ky*kx][NCO] so each
//    wave's per-ci weights are one contiguous run -> few big s_load batches,
//    fewer lgkmcnt(0) drains mixing with activation ds_reads.
//  - #pragma unroll 2 on the ci loop for cross-iteration load/FMA overlap.
// Everything else identical to round 15 (scalar guarded conv stores; 4-deep
// ppp prefetch; split-k x8 dense7 + reduce8 + psp7).
// All fp32; IIR op ordering bit-matches the reference scan.

#define TT 300

#define A1 0.9048374180359595f   // exp(-1/10)
#define C1 0.2718281828459045f   // e/10
#define A2 0.36787944117144233f  // exp(-1)
#define C2 2.718281828459045f    // e
#define KREF (20.0f * C2)
#define THETA_F 10.0f

typedef float v2f __attribute__((ext_vector_type(2)));

struct IIR {
  float p1, q1, p2, q2;
  __device__ IIR() : p1(0.f), q1(0.f), p2(0.f), q2(0.f) {}
  __device__ inline float step(float xin) {
    q1 = A1 * q1 + A1 * p1;
    float y = C1 * q1;
    p1 = A1 * p1 + xin;
    q2 = A2 * q2 + A2 * p2;
    float u = y - KREF * q2;
    float s = (u >= THETA_F) ? 1.0f : 0.0f;
    p2 = A2 * p2 + s;
    return s;
  }
};

// ---------------- generic tiled transpose: in[R][C] -> out[C][R] ----------------
__global__ __launch_bounds__(256) void transpose_rc(const float* __restrict__ in,
                                                    float* __restrict__ out,
                                                    int R, int C) {
  __shared__ float tile[64][65];
  int c0 = blockIdx.x * 64, r0 = blockIdx.y * 64;
  int tx = threadIdx.x & 63, ty = threadIdx.x >> 6;
  for (int i = ty; i < 64; i += 4) {
    int r = r0 + i, c = c0 + tx;
    if (r < R && c < C) tile[i][tx] = in[(long)r * C + c];
  }
  __syncthreads();
  for (int i = ty; i < 64; i += 4) {
    int c = c0 + i, r = r0 + tx;
    if (c < C && r < R) out[(long)c * R + r] = tile[tx][i];
  }
}

// ---------------- conv-weight relayout, one launch ----------------
// Wc[co][ci][ky][kx] -> Wg[g][ci][ky*kx][NCO], co = g*NCO + j.
// Each wave (co-group g) then reads contiguous NCO-float chunks, and a whole
// ci's weights (KS*KS*NCO floats) are one contiguous run -> batched s_loads.
__global__ __launch_bounds__(256) void prep_w(const float* __restrict__ Wc1,
                                              const float* __restrict__ Wc2,
                                              const float* __restrict__ Wc3,
                                              float* __restrict__ Wg1,
                                              float* __restrict__ Wg2,
                                              float* __restrict__ Wg3) {
  int i = blockIdx.x * 256 + threadIdx.x;
  if (i < 1200) {  // L1: CIN*KS*KS = 50, NCO = 6
    int co = i / 50, rem = i % 50;
    int g = co / 6, j = co % 6;
    Wg1[(g * 50 + rem) * 6 + j] = Wc1[i];
    return;
  }
  i -= 1200;
  if (i < 10368) {  // L3: CIN*KS*KS = 216, NCO = 12
    int co = i / 216, rem = i % 216;
    int g = co / 12, j = co % 12;
    Wg2[(g * 216 + rem) * 12 + j] = Wc2[i];
    return;
  }
  i -= 10368;
  if (i < 41472) {  // L5: CIN*KS*KS = 432, NCO = 24
    int co = i / 432, rem = i % 432;
    int g = co / 24, j = co % 24;
    Wg3[(g * 432 + rem) * 24 + j] = Wc3[i];
  }
}

// ---------------- per-timestep conv, time-major, 4 waves/block ----------------
// S: [T][B][CIN][HW][HW], Wt: [g][CIN][KS*KS][NCO], U: [T][B][CO][HW][HW]
// z=1: the 4 waves of a block cover all CO (4*NCO == CO); input tile staged
// once and each activation window read once per wave for NCO outputs.
// Scalar guarded stores ONLY (float2-pair stores caused 4x HBM write
// amplification on L1 -- round 14 counters).
template <int CIN, int HW, int KS, int PAD, int CO, int NCO, int NPX, int RS, int NITER>
__global__ __launch_bounds__(256) void conv_tm8(const float* __restrict__ S,
                                                const float* __restrict__ Wt,
                                                float* __restrict__ U) {
  constexpr int PH = HW + 2 * PAD;
  constexpr int TILE = CIN * PH * RS;
  constexpr int XG = (HW + NPX - 1) / NPX;
  constexpr int SLOTS = HW * XG;
  constexpr int WIN = NPX + KS - 1;
  constexpr int NP2 = NPX / 2;
  __shared__ float lin[TILE + WIN];
  const int t = blockIdx.x, b = blockIdx.y, B = gridDim.y;

  for (int i = threadIdx.x; i < TILE + WIN; i += 256) lin[i] = 0.f;
  __syncthreads();
  const float* src = S + ((long)t * B + b) * (CIN * HW * HW);
  for (int i = threadIdx.x; i < CIN * HW * HW; i += 256) {
    int ci = i / (HW * HW), r = i % (HW * HW);
    int iy = r / HW, ix = r % HW;
    lin[ci * PH * RS + (iy + PAD) * RS + ix + PAD] = src[i];
  }
  __syncthreads();

  const int lane = threadIdx.x & 63;
  const int g = blockIdx.z * 4 + __builtin_amdgcn_readfirstlane(threadIdx.x >> 6);
  const int co0 = g * NCO;
  const float* wb = Wt + (long)g * (CIN * KS * KS * NCO);

  for (int it = 0; it < NITER; ++it) {
    int slot = lane + 64 * it;
    bool act = slot < SLOTS;
    int ss = act ? slot : 0;
    int y = ss / XG, x0 = (ss % XG) * NPX;
    const float* base = lin + y * RS + x0;
    v2f acc[NCO][NP2];
#pragma unroll
    for (int j = 0; j < NCO; ++j)
#pragma unroll
      for (int p = 0; p < NP2; ++p) acc[j][p] = (v2f)(0.f);

#pragma unroll 2
    for (int ci = 0; ci < CIN; ++ci) {
      const float* bp = base + ci * (PH * RS);
      const float* wc = wb + ci * (KS * KS * NCO);
#pragma unroll
      for (int dy = 0; dy < KS; ++dy) {
        float win[WIN];
#pragma unroll
        for (int k = 0; k < WIN; ++k) win[k] = bp[dy * RS + k];
#pragma unroll
        for (int dx = 0; dx < KS; ++dx) {
          float wv[NCO];
#pragma unroll
          for (int j = 0; j < NCO; ++j)
            wv[j] = wc[(dy * KS + dx) * NCO + j];
#pragma unroll
          for (int p = 0; p < NP2; ++p) {
            v2f xp;
            xp.x = win[2 * p + dx];
            xp.y = win[2 * p + 1 + dx];
#pragma unroll
            for (int j = 0; j < NCO; ++j)
              acc[j][p] += xp * wv[j];
          }
        }
      }
    }
    if (act) {
      float* up = U + (((long)t * B + b) * CO + co0) * (HW * HW) + y * HW + x0;
#pragma unroll
      for (int j = 0; j < NCO; ++j)
#pragma unroll
        for (int p = 0; p < NP2; ++p) {
          if (x0 + 2 * p < HW) up[j * (HW * HW) + 2 * p] = acc[j][p].x;
          if (x0 + 2 * p + 1 < HW) up[j * (HW * HW) + 2 * p + 1] = acc[j][p].y;
        }
    }
  }
}

// ---------------- fused psp->pool(x11)->psp, 4 lanes/neuron, 4-deep prefetch ----------------
template <int C, int HIN, int HOUT>
__global__ __launch_bounds__(128) void ppp4_tm(const float* __restrict__ U,
                                               float* __restrict__ out, int B) {
  const int NOUT = B * C * HOUT * HOUT;
  const long SIN = (long)B * C * HIN * HIN;
  int id = blockIdx.x * 128 + threadIdx.x;
  int sub = id & 3, m = id >> 2;
  bool active = m < NOUT;
  int mm = active ? m : 0;
  int x2 = mm % HOUT;
  int y2 = (mm / HOUT) % HOUT;
  int c = (mm / (HOUT * HOUT)) % C;
  int b = mm / (C * HOUT * HOUT);
  int iy = 2 * y2 + (sub >> 1), ix = 2 * x2 + (sub & 1);
  bool valid = active && iy < HIN && ix < HIN;
  const float* base = U + ((long)(b * C + c) * HIN + iy) * HIN + ix;
  bool writer = active && (sub == 0);
  float* op = out + mm;
  IIR si, so;
  float pr0 = valid ? base[0] : 0.f;
  float pr1 = valid ? base[SIN] : 0.f;
  float pr2 = valid ? base[2 * SIN] : 0.f;
  float pr3 = valid ? base[3 * SIN] : 0.f;
  for (int tb = 0; tb < TT; tb += 4) {
    float a0 = pr0, a1 = pr1, a2 = pr2, a3 = pr3;
    const float* nb = base + (long)(tb + 4) * SIN;  // last iter overreads into ws
    pr0 = valid ? nb[0] : 0.f;
    pr1 = valid ? nb[SIN] : 0.f;
    pr2 = valid ? nb[2 * SIN] : 0.f;
    pr3 = valid ? nb[3 * SIN] : 0.f;
    {
      float s = si.step(a0);
      float v = s + __shfl_xor(s, 1); v += __shfl_xor(v, 2);
      float o = so.step(11.0f * v);
      if (writer) op[(long)tb * NOUT] = o;
    }
    {
      float s = si.step(a1);
      float v = s + __shfl_xor(s, 1); v += __shfl_xor(v, 2);
      float o = so.step(11.0f * v);
      if (writer) op[(long)(tb + 1) * NOUT] = o;
    }
    {
      float s = si.step(a2);
      float v = s + __shfl_xor(s, 1); v += __shfl_xor(v, 2);
      float o = so.step(11.0f * v);
      if (writer) op[(long)(tb + 2) * NOUT] = o;
    }
    {
      float s = si.step(a3);
      float v = s + __shfl_xor(s, 1); v += __shfl_xor(v, 2);
      float o = so.step(11.0f * v);
      if (writer) op[(long)(tb + 3) * NOUT] = o;
    }
  }
}

// ---------------- dense7k: split-k x8 GEMM, P[kz][row][o] partials ----------------
__global__ __launch_bounds__(256) void dense7k(const float* __restrict__ S,
                                               const float* __restrict__ Wt,
                                               float* __restrict__ P) {
  const int r0 = blockIdx.x * 16 + (threadIdx.x >> 6) * 4;
  const int kz = blockIdx.y;
  const int lane = threadIdx.x & 63;
  const float* s0 = S + (long)r0 * 2400;
  const float* s1 = s0 + 2400;
  const float* s2 = s0 + 4800;
  const float* s3 = s0 + 7200;
  const float* wp = Wt + lane * 4;
  v2f aA[4], aB[4];
#pragma unroll
  for (int o = 0; o < 4; ++o) { aA[o] = (v2f)(0.f); aB[o] = (v2f)(0.f); }
  const int k0 = kz * 300, k1 = k0 + 300;
  for (int k = k0; k < k1; k += 4) {
    float4 a0 = *(const float4*)(s0 + k);
    float4 a1 = *(const float4*)(s1 + k);
    float4 a2 = *(const float4*)(s2 + k);
    float4 a3 = *(const float4*)(s3 + k);
#define DSTEP(KK, AX)                                                        \
    {                                                                        \
      float4 w = *(const float4*)(wp + (long)(k + KK) * 256);                \
      v2f pA, pB;                                                            \
      pA.x = a0.AX; pA.y = a1.AX; pB.x = a2.AX; pB.y = a3.AX;                \
      aA[0] += pA * w.x; aA[1] += pA * w.y; aA[2] += pA * w.z; aA[3] += pA * w.w; \
      aB[0] += pB * w.x; aB[1] += pB * w.y; aB[2] += pB * w.z; aB[3] += pB * w.w; \
    }
    DSTEP(0, x) DSTEP(1, y) DSTEP(2, z) DSTEP(3, w)
#undef DSTEP
  }
  float* p = P + (long)kz * 307200 + (long)r0 * 256 + lane * 4;
#pragma unroll
  for (int o = 0; o < 4; ++o) p[o] = aA[o].x;
#pragma unroll
  for (int o = 0; o < 4; ++o) p[256 + o] = aA[o].y;
#pragma unroll
  for (int o = 0; o < 4; ++o) p[512 + o] = aB[o].x;
#pragma unroll
  for (int o = 0; o < 4; ++o) p[768 + o] = aB[o].y;
}

// ---------------- reduce8: U7 = sum of 8 partials (float4, ascending kz) ----------------
__global__ __launch_bounds__(256) void reduce8(const float* __restrict__ P,
                                               float* __restrict__ U7) {
  int i = blockIdx.x * 256 + threadIdx.x;  // over 76800 float4s
  if (i >= 76800) return;
  const float4* p = (const float4*)P;
  float4 a = p[i];
#pragma unroll
  for (int kz = 1; kz < 8; ++kz) {
    float4 b = p[(long)kz * 76800 + i];
    a.x += b.x; a.y += b.y; a.z += b.z; a.w += b.w;
  }
  ((float4*)U7)[i] = a;
}

// ---------------- psp7: psp+spike over U7, 4-deep prefetch ----------------
__global__ __launch_bounds__(128) void psp7(const float* __restrict__ U7,
                                            float* __restrict__ out) {
  int n = blockIdx.x * 128 + threadIdx.x;  // 0..1023
  IIR st;
  float pr0 = U7[n], pr1 = U7[1024 + n], pr2 = U7[2048 + n], pr3 = U7[3072 + n];
  for (int tb = 0; tb < TT; tb += 4) {
    float a0 = pr0, a1 = pr1, a2 = pr2, a3 = pr3;
    const float* nb = U7 + (long)(tb + 4) * 1024 + n;  // overreads into ws at end
    pr0 = nb[0]; pr1 = nb[1024]; pr2 = nb[2048]; pr3 = nb[3072];
    out[(long)tb * 1024 + n] = st.step(a0);
    out[(long)(tb + 1) * 1024 + n] = st.step(a1);
    out[(long)(tb + 2) * 1024 + n] = st.step(a2);
    out[(long)(tb + 3) * 1024 + n] = st.step(a3);
  }
}

// ---------------- dense8 ----------------
__global__ __launch_bounds__(256) void dense8(const float* __restrict__ S,
                                              const float* __restrict__ W,
                                              float* __restrict__ U) {
  int id = blockIdx.x * 256 + threadIdx.x;
  if (id >= 12000) return;
  int o = id % 10, row = id / 10;
  const float* sr = S + (long)row * 256;
  const float* wr = W + o * 256;
  float acc = 0.f;
  for (int k = 0; k < 256; k += 4) {
    float4 a = *(const float4*)(sr + k);
    float4 w = *(const float4*)(wr + k);
    acc += a.x * w.x; acc += a.y * w.y; acc += a.z * w.z; acc += a.w * w.w;
  }
  U[id] = acc;
}

// ---------------- final psp+spike + transpose to (B,10,T), prefetched ----------------
__global__ void psp8_out(const float* __restrict__ U, float* __restrict__ out) {
  int n = threadIdx.x;
  bool act = n < 40;
  int nn = act ? n : 0;
  IIR st;
  float pr0 = U[nn], pr1 = U[40 + nn], pr2 = U[80 + nn], pr3 = U[120 + nn];
  for (int tb = 0; tb < TT; tb += 4) {
    float a0 = pr0, a1 = pr1, a2 = pr2, a3 = pr3;
    const float* nb = U + (long)(tb + 4) * 40 + nn;  // overreads into ws at end
    pr0 = nb[0]; pr1 = nb[40]; pr2 = nb[80]; pr3 = nb[120];
    float o0 = st.step(a0), o1 = st.step(a1), o2 = st.step(a2), o3 = st.step(a3);
    if (act) {
      out[nn * TT + tb] = o0;
      out[nn * TT + tb + 1] = o1;
      out[nn * TT + tb + 2] = o2;
      out[nn * TT + tb + 3] = o3;
    }
  }
}

extern "C" void kernel_launch(void* const* d_in, const int* in_sizes, int n_in,
                              void* d_out, int out_size, void* d_ws, size_t ws_size,
                              hipStream_t stream) {
  const float* s_in = (const float*)d_in[0];
  const float* Wc1  = (const float*)d_in[1];
  const float* Wc2  = (const float*)d_in[2];
  const float* Wc3  = (const float*)d_in[3];
  const float* Wd4a = (const float*)d_in[4];
  const float* Wd4b = (const float*)d_in[5];

  float* Buf1 = (float*)d_ws;            // 33,292,800 floats (U1/U3/U5)
  float* Buf2 = Buf1 + 33292800;
  float* s2   = Buf2;                    //  8,323,200
  float* s4   = Buf2 + 8323200;          //  4,665,600
  float* Wt4a = Buf2 + 12988800;         //    614,400
  float* T0   = Buf2 + 13910400;         //  2,774,400
  float* Wt1  = Buf2 + 16684800;         //      1,200
  float* Wt2  = Buf2 + 16686000;         //     10,368
  float* Wt3  = Buf2 + 16696368;         //     41,472
  float* s7   = Buf2 + 16737840;         //    307,200
  float* P7   = Buf2 + 17045040;         //  2,457,600 (8 x 307,200 partials)
  float* U7   = Buf2 + 19502640;         //    307,200
  float* s6   = Buf2;                    //  2,880,000 (s2 region, dead by L6)
  float* U8   = Buf1;                    //     12,000 (Buf1 dead by L8)

  // prep: input -> time-major; Wd4a -> [k][o]; conv weights -> [g][ci][k][NCO]
  transpose_rc<<<dim3(5, 145), 256, 0, stream>>>(s_in, T0, 9248, 300);
  transpose_rc<<<dim3(38, 4), 256, 0, stream>>>(Wd4a, Wt4a, 256, 2400);
  prep_w<<<208, 256, 0, stream>>>(Wc1, Wc2, Wc3, Wt1, Wt2, Wt3);

  // L1: conv 2->24 k5 p2 (4 waves x NCO=6, z=1, NPX=4, RS=39, NITER=5) -> 1200 blocks
  conv_tm8<2, 34, 5, 2, 24, 6, 4, 39, 5><<<dim3(300, 4), 256, 0, stream>>>(T0, Wt1, Buf1);
  // L1-psp + pool 34->17 + psp -> s2
  ppp4_tm<24, 34, 17><<<867, 128, 0, stream>>>(Buf1, s2, 4);
  // L3: conv 24->48 k3 p1 (4 waves x NCO=12, z=1, NPX=6, RS=19, NITER=1) -> 1200 blocks
  conv_tm8<24, 17, 3, 1, 48, 12, 6, 19, 1><<<dim3(300, 4), 256, 0, stream>>>(s2, Wt2, Buf1);
  // L3-psp + pool 17->9 + psp -> s4
  ppp4_tm<48, 17, 9><<<486, 128, 0, stream>>>(Buf1, s4, 4);
  // L5: conv 48->96 k3 p1 (4 waves x NCO=24, z=1, NPX=2, RS=13, NITER=1) -> 1200 blocks
  conv_tm8<48, 9, 3, 1, 96, 24, 2, 13, 1><<<dim3(300, 4), 256, 0, stream>>>(s4, Wt3, Buf1);
  // L5-psp + pool 9->5 + psp -> s6
  ppp4_tm<96, 9, 5><<<300, 128, 0, stream>>>(Buf1, s6, 4);
  // L7: dense 2400->256 split-k x8 ; fold partials ; psp -> s7
  dense7k<<<dim3(75, 8), 256, 0, stream>>>(s6, Wt4a, P7);
  reduce8<<<300, 256, 0, stream>>>(P7, U7);
  psp7<<<8, 128, 0, stream>>>(U7, s7);
  // L8: dense 256->10 ; psp + output transpose
  dense8<<<47, 256, 0, stream>>>(s7, Wd4b, U8);
  psp8_out<<<1, 64, 0, stream>>>(U8, (float*)d_out);
}

// Round 2
// 705.892 us; speedup vs baseline: 1.1130x; 1.1130x over previous
//
#include <hip/hip_runtime.h>

// SLAYER SNN forward, round 17 = round 15 geometry (z=2 convs, NCO 3/6/12)
// with two retained/new tweaks:
//  - weights relaid per co-group contiguous: Wg[g][ci][ky*kx][NCO], g=co/NCO
//    (8 groups per layer). Each wave's per-ci weights are one contiguous run
//    -> batched s_loads, fewer lgkm sync points. (r16 counters confirmed the
//    layout's traffic signature; the r16 regression traced to NCO doubling,
//    which is reverted here.)
//  - L5 LDS tile RS 13 -> 11 (23.3KB vs 27.6KB): LDS-limited occupancy
//    6 blocks/CU instead of 5 (L5 was 42% occupancy, 30% issue-idle).
// No ci-loop unroll pragma (confounded suspect in r16's regression).
// Everything else identical to round 15 (scalar guarded conv stores; 4-deep
// ppp prefetch; split-k x8 dense7 + reduce8 + psp7).
// All fp32; IIR op ordering bit-matches the reference scan.

#define TT 300

#define A1 0.9048374180359595f   // exp(-1/10)
#define C1 0.2718281828459045f   // e/10
#define A2 0.36787944117144233f  // exp(-1)
#define C2 2.718281828459045f    // e
#define KREF (20.0f * C2)
#define THETA_F 10.0f

typedef float v2f __attribute__((ext_vector_type(2)));

struct IIR {
  float p1, q1, p2, q2;
  __device__ IIR() : p1(0.f), q1(0.f), p2(0.f), q2(0.f) {}
  __device__ inline float step(float xin) {
    q1 = A1 * q1 + A1 * p1;
    float y = C1 * q1;
    p1 = A1 * p1 + xin;
    q2 = A2 * q2 + A2 * p2;
    float u = y - KREF * q2;
    float s = (u >= THETA_F) ? 1.0f : 0.0f;
    p2 = A2 * p2 + s;
    return s;
  }
};

// ---------------- generic tiled transpose: in[R][C] -> out[C][R] ----------------
__global__ __launch_bounds__(256) void transpose_rc(const float* __restrict__ in,
                                                    float* __restrict__ out,
                                                    int R, int C) {
  __shared__ float tile[64][65];
  int c0 = blockIdx.x * 64, r0 = blockIdx.y * 64;
  int tx = threadIdx.x & 63, ty = threadIdx.x >> 6;
  for (int i = ty; i < 64; i += 4) {
    int r = r0 + i, c = c0 + tx;
    if (r < R && c < C) tile[i][tx] = in[(long)r * C + c];
  }
  __syncthreads();
  for (int i = ty; i < 64; i += 4) {
    int c = c0 + i, r = r0 + tx;
    if (c < C && r < R) out[(long)c * R + r] = tile[tx][i];
  }
}

// ---------------- conv-weight relayout, one launch ----------------
// Wc[co][ci][ky][kx] -> Wg[g][ci][ky*kx][NCO], co = g*NCO + j.
// NCO per layer: L1=3, L3=6, L5=12 (8 groups each).
__global__ __launch_bounds__(256) void prep_w(const float* __restrict__ Wc1,
                                              const float* __restrict__ Wc2,
                                              const float* __restrict__ Wc3,
                                              float* __restrict__ Wg1,
                                              float* __restrict__ Wg2,
                                              float* __restrict__ Wg3) {
  int i = blockIdx.x * 256 + threadIdx.x;
  if (i < 1200) {  // L1: CIN*KS*KS = 50, NCO = 3
    int co = i / 50, rem = i % 50;
    int g = co / 3, j = co % 3;
    Wg1[(g * 50 + rem) * 3 + j] = Wc1[i];
    return;
  }
  i -= 1200;
  if (i < 10368) {  // L3: CIN*KS*KS = 216, NCO = 6
    int co = i / 216, rem = i % 216;
    int g = co / 6, j = co % 6;
    Wg2[(g * 216 + rem) * 6 + j] = Wc2[i];
    return;
  }
  i -= 10368;
  if (i < 41472) {  // L5: CIN*KS*KS = 432, NCO = 12
    int co = i / 432, rem = i % 432;
    int g = co / 12, j = co % 12;
    Wg3[(g * 432 + rem) * 12 + j] = Wc3[i];
  }
}

// ---------------- per-timestep conv, time-major, 4 waves/block, z co-halves ----------------
// S: [T][B][CIN][HW][HW], Wt: [g][CIN][KS*KS][NCO], U: [T][B][CO][HW][HW]
// g = blockIdx.z*4 + wave; co0 = g*NCO.
// Scalar guarded stores ONLY (float2-pair stores caused 4x HBM write
// amplification on L1 -- round 14 counters).
template <int CIN, int HW, int KS, int PAD, int CO, int NCO, int NPX, int RS, int NITER>
__global__ __launch_bounds__(256) void conv_tm8(const float* __restrict__ S,
                                                const float* __restrict__ Wt,
                                                float* __restrict__ U) {
  constexpr int PH = HW + 2 * PAD;
  constexpr int TILE = CIN * PH * RS;
  constexpr int XG = (HW + NPX - 1) / NPX;
  constexpr int SLOTS = HW * XG;
  constexpr int WIN = NPX + KS - 1;
  constexpr int NP2 = NPX / 2;
  __shared__ float lin[TILE + WIN];
  const int t = blockIdx.x, b = blockIdx.y, B = gridDim.y;

  for (int i = threadIdx.x; i < TILE + WIN; i += 256) lin[i] = 0.f;
  __syncthreads();
  const float* src = S + ((long)t * B + b) * (CIN * HW * HW);
  for (int i = threadIdx.x; i < CIN * HW * HW; i += 256) {
    int ci = i / (HW * HW), r = i % (HW * HW);
    int iy = r / HW, ix = r % HW;
    lin[ci * PH * RS + (iy + PAD) * RS + ix + PAD] = src[i];
  }
  __syncthreads();

  const int lane = threadIdx.x & 63;
  const int g = blockIdx.z * 4 + __builtin_amdgcn_readfirstlane(threadIdx.x >> 6);
  const int co0 = g * NCO;
  const float* wb = Wt + (long)g * (CIN * KS * KS * NCO);

  for (int it = 0; it < NITER; ++it) {
    int slot = lane + 64 * it;
    bool act = slot < SLOTS;
    int ss = act ? slot : 0;
    int y = ss / XG, x0 = (ss % XG) * NPX;
    const float* base = lin + y * RS + x0;
    v2f acc[NCO][NP2];
#pragma unroll
    for (int j = 0; j < NCO; ++j)
#pragma unroll
      for (int p = 0; p < NP2; ++p) acc[j][p] = (v2f)(0.f);

    for (int ci = 0; ci < CIN; ++ci) {
      const float* bp = base + ci * (PH * RS);
      const float* wc = wb + ci * (KS * KS * NCO);
#pragma unroll
      for (int dy = 0; dy < KS; ++dy) {
        float win[WIN];
#pragma unroll
        for (int k = 0; k < WIN; ++k) win[k] = bp[dy * RS + k];
#pragma unroll
        for (int dx = 0; dx < KS; ++dx) {
          float wv[NCO];
#pragma unroll
          for (int j = 0; j < NCO; ++j)
            wv[j] = wc[(dy * KS + dx) * NCO + j];
#pragma unroll
          for (int p = 0; p < NP2; ++p) {
            v2f xp;
            xp.x = win[2 * p + dx];
            xp.y = win[2 * p + 1 + dx];
#pragma unroll
            for (int j = 0; j < NCO; ++j)
              acc[j][p] += xp * wv[j];
          }
        }
      }
    }
    if (act) {
      float* up = U + (((long)t * B + b) * CO + co0) * (HW * HW) + y * HW + x0;
#pragma unroll
      for (int j = 0; j < NCO; ++j)
#pragma unroll
        for (int p = 0; p < NP2; ++p) {
          if (x0 + 2 * p < HW) up[j * (HW * HW) + 2 * p] = acc[j][p].x;
          if (x0 + 2 * p + 1 < HW) up[j * (HW * HW) + 2 * p + 1] = acc[j][p].y;
        }
    }
  }
}

// ---------------- fused psp->pool(x11)->psp, 4 lanes/neuron, 4-deep prefetch ----------------
template <int C, int HIN, int HOUT>
__global__ __launch_bounds__(128) void ppp4_tm(const float* __restrict__ U,
                                               float* __restrict__ out, int B) {
  const int NOUT = B * C * HOUT * HOUT;
  const long SIN = (long)B * C * HIN * HIN;
  int id = blockIdx.x * 128 + threadIdx.x;
  int sub = id & 3, m = id >> 2;
  bool active = m < NOUT;
  int mm = active ? m : 0;
  int x2 = mm % HOUT;
  int y2 = (mm / HOUT) % HOUT;
  int c = (mm / (HOUT * HOUT)) % C;
  int b = mm / (C * HOUT * HOUT);
  int iy = 2 * y2 + (sub >> 1), ix = 2 * x2 + (sub & 1);
  bool valid = active && iy < HIN && ix < HIN;
  const float* base = U + ((long)(b * C + c) * HIN + iy) * HIN + ix;
  bool writer = active && (sub == 0);
  float* op = out + mm;
  IIR si, so;
  float pr0 = valid ? base[0] : 0.f;
  float pr1 = valid ? base[SIN] : 0.f;
  float pr2 = valid ? base[2 * SIN] : 0.f;
  float pr3 = valid ? base[3 * SIN] : 0.f;
  for (int tb = 0; tb < TT; tb += 4) {
    float a0 = pr0, a1 = pr1, a2 = pr2, a3 = pr3;
    const float* nb = base + (long)(tb + 4) * SIN;  // last iter overreads into ws
    pr0 = valid ? nb[0] : 0.f;
    pr1 = valid ? nb[SIN] : 0.f;
    pr2 = valid ? nb[2 * SIN] : 0.f;
    pr3 = valid ? nb[3 * SIN] : 0.f;
    {
      float s = si.step(a0);
      float v = s + __shfl_xor(s, 1); v += __shfl_xor(v, 2);
      float o = so.step(11.0f * v);
      if (writer) op[(long)tb * NOUT] = o;
    }
    {
      float s = si.step(a1);
      float v = s + __shfl_xor(s, 1); v += __shfl_xor(v, 2);
      float o = so.step(11.0f * v);
      if (writer) op[(long)(tb + 1) * NOUT] = o;
    }
    {
      float s = si.step(a2);
      float v = s + __shfl_xor(s, 1); v += __shfl_xor(v, 2);
      float o = so.step(11.0f * v);
      if (writer) op[(long)(tb + 2) * NOUT] = o;
    }
    {
      float s = si.step(a3);
      float v = s + __shfl_xor(s, 1); v += __shfl_xor(v, 2);
      float o = so.step(11.0f * v);
      if (writer) op[(long)(tb + 3) * NOUT] = o;
    }
  }
}

// ---------------- dense7k: split-k x8 GEMM, P[kz][row][o] partials ----------------
__global__ __launch_bounds__(256) void dense7k(const float* __restrict__ S,
                                               const float* __restrict__ Wt,
                                               float* __restrict__ P) {
  const int r0 = blockIdx.x * 16 + (threadIdx.x >> 6) * 4;
  const int kz = blockIdx.y;
  const int lane = threadIdx.x & 63;
  const float* s0 = S + (long)r0 * 2400;
  const float* s1 = s0 + 2400;
  const float* s2 = s0 + 4800;
  const float* s3 = s0 + 7200;
  const float* wp = Wt + lane * 4;
  v2f aA[4], aB[4];
#pragma unroll
  for (int o = 0; o < 4; ++o) { aA[o] = (v2f)(0.f); aB[o] = (v2f)(0.f); }
  const int k0 = kz * 300, k1 = k0 + 300;
  for (int k = k0; k < k1; k += 4) {
    float4 a0 = *(const float4*)(s0 + k);
    float4 a1 = *(const float4*)(s1 + k);
    float4 a2 = *(const float4*)(s2 + k);
    float4 a3 = *(const float4*)(s3 + k);
#define DSTEP(KK, AX)                                                        \
    {                                                                        \
      float4 w = *(const float4*)(wp + (long)(k + KK) * 256);                \
      v2f pA, pB;                                                            \
      pA.x = a0.AX; pA.y = a1.AX; pB.x = a2.AX; pB.y = a3.AX;                \
      aA[0] += pA * w.x; aA[1] += pA * w.y; aA[2] += pA * w.z; aA[3] += pA * w.w; \
      aB[0] += pB * w.x; aB[1] += pB * w.y; aB[2] += pB * w.z; aB[3] += pB * w.w; \
    }
    DSTEP(0, x) DSTEP(1, y) DSTEP(2, z) DSTEP(3, w)
#undef DSTEP
  }
  float* p = P + (long)kz * 307200 + (long)r0 * 256 + lane * 4;
#pragma unroll
  for (int o = 0; o < 4; ++o) p[o] = aA[o].x;
#pragma unroll
  for (int o = 0; o < 4; ++o) p[256 + o] = aA[o].y;
#pragma unroll
  for (int o = 0; o < 4; ++o) p[512 + o] = aB[o].x;
#pragma unroll
  for (int o = 0; o < 4; ++o) p[768 + o] = aB[o].y;
}

// ---------------- reduce8: U7 = sum of 8 partials (float4, ascending kz) ----------------
__global__ __launch_bounds__(256) void reduce8(const float* __restrict__ P,
                                               float* __restrict__ U7) {
  int i = blockIdx.x * 256 + threadIdx.x;  // over 76800 float4s
  if (i >= 76800) return;
  const float4* p = (const float4*)P;
  float4 a = p[i];
#pragma unroll
  for (int kz = 1; kz < 8; ++kz) {
    float4 b = p[(long)kz * 76800 + i];
    a.x += b.x; a.y += b.y; a.z += b.z; a.w += b.w;
  }
  ((float4*)U7)[i] = a;
}

// ---------------- psp7: psp+spike over U7, 4-deep prefetch ----------------
__global__ __launch_bounds__(128) void psp7(const float* __restrict__ U7,
                                            float* __restrict__ out) {
  int n = blockIdx.x * 128 + threadIdx.x;  // 0..1023
  IIR st;
  float pr0 = U7[n], pr1 = U7[1024 + n], pr2 = U7[2048 + n], pr3 = U7[3072 + n];
  for (int tb = 0; tb < TT; tb += 4) {
    float a0 = pr0, a1 = pr1, a2 = pr2, a3 = pr3;
    const float* nb = U7 + (long)(tb + 4) * 1024 + n;  // overreads into ws at end
    pr0 = nb[0]; pr1 = nb[1024]; pr2 = nb[2048]; pr3 = nb[3072];
    out[(long)tb * 1024 + n] = st.step(a0);
    out[(long)(tb + 1) * 1024 + n] = st.step(a1);
    out[(long)(tb + 2) * 1024 + n] = st.step(a2);
    out[(long)(tb + 3) * 1024 + n] = st.step(a3);
  }
}

// ---------------- dense8 ----------------
__global__ __launch_bounds__(256) void dense8(const float* __restrict__ S,
                                              const float* __restrict__ W,
                                              float* __restrict__ U) {
  int id = blockIdx.x * 256 + threadIdx.x;
  if (id >= 12000) return;
  int o = id % 10, row = id / 10;
  const float* sr = S + (long)row * 256;
  const float* wr = W + o * 256;
  float acc = 0.f;
  for (int k = 0; k < 256; k += 4) {
    float4 a = *(const float4*)(sr + k);
    float4 w = *(const float4*)(wr + k);
    acc += a.x * w.x; acc += a.y * w.y; acc += a.z * w.z; acc += a.w * w.w;
  }
  U[id] = acc;
}

// ---------------- final psp+spike + transpose to (B,10,T), prefetched ----------------
__global__ void psp8_out(const float* __restrict__ U, float* __restrict__ out) {
  int n = threadIdx.x;
  bool act = n < 40;
  int nn = act ? n : 0;
  IIR st;
  float pr0 = U[nn], pr1 = U[40 + nn], pr2 = U[80 + nn], pr3 = U[120 + nn];
  for (int tb = 0; tb < TT; tb += 4) {
    float a0 = pr0, a1 = pr1, a2 = pr2, a3 = pr3;
    const float* nb = U + (long)(tb + 4) * 40 + nn;  // overreads into ws at end
    pr0 = nb[0]; pr1 = nb[40]; pr2 = nb[80]; pr3 = nb[120];
    float o0 = st.step(a0), o1 = st.step(a1), o2 = st.step(a2), o3 = st.step(a3);
    if (act) {
      out[nn * TT + tb] = o0;
      out[nn * TT + tb + 1] = o1;
      out[nn * TT + tb + 2] = o2;
      out[nn * TT + tb + 3] = o3;
    }
  }
}

extern "C" void kernel_launch(void* const* d_in, const int* in_sizes, int n_in,
                              void* d_out, int out_size, void* d_ws, size_t ws_size,
                              hipStream_t stream) {
  const float* s_in = (const float*)d_in[0];
  const float* Wc1  = (const float*)d_in[1];
  const float* Wc2  = (const float*)d_in[2];
  const float* Wc3  = (const float*)d_in[3];
  const float* Wd4a = (const float*)d_in[4];
  const float* Wd4b = (const float*)d_in[5];

  float* Buf1 = (float*)d_ws;            // 33,292,800 floats (U1/U3/U5)
  float* Buf2 = Buf1 + 33292800;
  float* s2   = Buf2;                    //  8,323,200
  float* s4   = Buf2 + 8323200;          //  4,665,600
  float* Wt4a = Buf2 + 12988800;         //    614,400
  float* T0   = Buf2 + 13910400;         //  2,774,400
  float* Wt1  = Buf2 + 16684800;         //      1,200
  float* Wt2  = Buf2 + 16686000;         //     10,368
  float* Wt3  = Buf2 + 16696368;         //     41,472
  float* s7   = Buf2 + 16737840;         //    307,200
  float* P7   = Buf2 + 17045040;         //  2,457,600 (8 x 307,200 partials)
  float* U7   = Buf2 + 19502640;         //    307,200
  float* s6   = Buf2;                    //  2,880,000 (s2 region, dead by L6)
  float* U8   = Buf1;                    //     12,000 (Buf1 dead by L8)

  // prep: input -> time-major; Wd4a -> [k][o]; conv weights -> [g][ci][k][NCO]
  transpose_rc<<<dim3(5, 145), 256, 0, stream>>>(s_in, T0, 9248, 300);
  transpose_rc<<<dim3(38, 4), 256, 0, stream>>>(Wd4a, Wt4a, 256, 2400);
  prep_w<<<208, 256, 0, stream>>>(Wc1, Wc2, Wc3, Wt1, Wt2, Wt3);

  // L1: conv 2->24 k5 p2 (4 waves x NCO=3, z=2, NPX=4, RS=39, NITER=5) -> 2400 blocks
  conv_tm8<2, 34, 5, 2, 24, 3, 4, 39, 5><<<dim3(300, 4, 2), 256, 0, stream>>>(T0, Wt1, Buf1);
  // L1-psp + pool 34->17 + psp -> s2
  ppp4_tm<24, 34, 17><<<867, 128, 0, stream>>>(Buf1, s2, 4);
  // L3: conv 24->48 k3 p1 (4 waves x NCO=6, z=2, NPX=6, RS=19, NITER=1) -> 2400 blocks
  conv_tm8<24, 17, 3, 1, 48, 6, 6, 19, 1><<<dim3(300, 4, 2), 256, 0, stream>>>(s2, Wt2, Buf1);
  // L3-psp + pool 17->9 + psp -> s4
  ppp4_tm<48, 17, 9><<<486, 128, 0, stream>>>(Buf1, s4, 4);
  // L5: conv 48->96 k3 p1 (4 waves x NCO=12, z=2, NPX=2, RS=11, NITER=1) -> 2400 blocks
  conv_tm8<48, 9, 3, 1, 96, 12, 2, 11, 1><<<dim3(300, 4, 2), 256, 0, stream>>>(s4, Wt3, Buf1);
  // L5-psp + pool 9->5 + psp -> s6
  ppp4_tm<96, 9, 5><<<300, 128, 0, stream>>>(Buf1, s6, 4);
  // L7: dense 2400->256 split-k x8 ; fold partials ; psp -> s7
  dense7k<<<dim3(75, 8), 256, 0, stream>>>(s6, Wt4a, P7);
  reduce8<<<300, 256, 0, stream>>>(P7, U7);
  psp7<<<8, 128, 0, stream>>>(U7, s7);
  // L8: dense 256->10 ; psp + output transpose
  dense8<<<47, 256, 0, stream>>>(s7, Wd4b, U8);
  psp8_out<<<1, 64, 0, stream>>>(U8, (float*)d_out);
}

// Round 3
// 701.422 us; speedup vs baseline: 1.1201x; 1.0064x over previous
//
#include <hip/hip_runtime.h>

// SLAYER SNN forward, round 18 = round 17 with 8-wave conv blocks (z merged
// into waves, NOT into NCO):
//  - conv blocks are 512 threads / 8 waves; wave w handles co-group w
//    (NCO 3/6/12 per wave, identical per-wave code to the proven r15 shape).
//    One block per (t,b): staging+init+barrier issued once instead of twice,
//    wave-occupancy ceiling 32/CU (4 blocks x 8 waves) vs r17's ~15.
//  - L5 RS back to 13 (r15 value): half the bank conflicts of RS=11; LDS no
//    longer binds occupancy (27.5KB x 4 blocks = 110KB < 160KB).
//  - weight layout Wg[g][ci][ky*kx][NCO] kept (8 groups/layer, r17-verified).
// Everything else identical to round 17 (scalar guarded conv stores; 4-deep
// ppp prefetch; split-k x8 dense7 + reduce8 + psp7).
// All fp32; IIR op ordering bit-matches the reference scan.

#define TT 300

#define A1 0.9048374180359595f   // exp(-1/10)
#define C1 0.2718281828459045f   // e/10
#define A2 0.36787944117144233f  // exp(-1)
#define C2 2.718281828459045f    // e
#define KREF (20.0f * C2)
#define THETA_F 10.0f

typedef float v2f __attribute__((ext_vector_type(2)));

struct IIR {
  float p1, q1, p2, q2;
  __device__ IIR() : p1(0.f), q1(0.f), p2(0.f), q2(0.f) {}
  __device__ inline float step(float xin) {
    q1 = A1 * q1 + A1 * p1;
    float y = C1 * q1;
    p1 = A1 * p1 + xin;
    q2 = A2 * q2 + A2 * p2;
    float u = y - KREF * q2;
    float s = (u >= THETA_F) ? 1.0f : 0.0f;
    p2 = A2 * p2 + s;
    return s;
  }
};

// ---------------- generic tiled transpose: in[R][C] -> out[C][R] ----------------
__global__ __launch_bounds__(256) void transpose_rc(const float* __restrict__ in,
                                                    float* __restrict__ out,
                                                    int R, int C) {
  __shared__ float tile[64][65];
  int c0 = blockIdx.x * 64, r0 = blockIdx.y * 64;
  int tx = threadIdx.x & 63, ty = threadIdx.x >> 6;
  for (int i = ty; i < 64; i += 4) {
    int r = r0 + i, c = c0 + tx;
    if (r < R && c < C) tile[i][tx] = in[(long)r * C + c];
  }
  __syncthreads();
  for (int i = ty; i < 64; i += 4) {
    int c = c0 + i, r = r0 + tx;
    if (c < C && r < R) out[(long)c * R + r] = tile[tx][i];
  }
}

// ---------------- conv-weight relayout, one launch ----------------
// Wc[co][ci][ky][kx] -> Wg[g][ci][ky*kx][NCO], co = g*NCO + j.
// NCO per layer: L1=3, L3=6, L5=12 (8 groups each -> one group per wave).
__global__ __launch_bounds__(256) void prep_w(const float* __restrict__ Wc1,
                                              const float* __restrict__ Wc2,
                                              const float* __restrict__ Wc3,
                                              float* __restrict__ Wg1,
                                              float* __restrict__ Wg2,
                                              float* __restrict__ Wg3) {
  int i = blockIdx.x * 256 + threadIdx.x;
  if (i < 1200) {  // L1: CIN*KS*KS = 50, NCO = 3
    int co = i / 50, rem = i % 50;
    int g = co / 3, j = co % 3;
    Wg1[(g * 50 + rem) * 3 + j] = Wc1[i];
    return;
  }
  i -= 1200;
  if (i < 10368) {  // L3: CIN*KS*KS = 216, NCO = 6
    int co = i / 216, rem = i % 216;
    int g = co / 6, j = co % 6;
    Wg2[(g * 216 + rem) * 6 + j] = Wc2[i];
    return;
  }
  i -= 10368;
  if (i < 41472) {  // L5: CIN*KS*KS = 432, NCO = 12
    int co = i / 432, rem = i % 432;
    int g = co / 12, j = co % 12;
    Wg3[(g * 432 + rem) * 12 + j] = Wc3[i];
  }
}

// ---------------- per-timestep conv, time-major, 8 waves/block ----------------
// S: [T][B][CIN][HW][HW], Wt: [g][CIN][KS*KS][NCO], U: [T][B][CO][HW][HW]
// One block per (t,b); wave w (0..7) computes co-group w (co0 = w*NCO).
// Staging done once per block by all 512 threads.
// Scalar guarded stores ONLY (float2-pair stores caused 4x HBM write
// amplification on L1 -- round 14 counters).
template <int CIN, int HW, int KS, int PAD, int CO, int NCO, int NPX, int RS, int NITER>
__global__ __launch_bounds__(512) void conv_tm8(const float* __restrict__ S,
                                                const float* __restrict__ Wt,
                                                float* __restrict__ U) {
  constexpr int PH = HW + 2 * PAD;
  constexpr int TILE = CIN * PH * RS;
  constexpr int XG = (HW + NPX - 1) / NPX;
  constexpr int SLOTS = HW * XG;
  constexpr int WIN = NPX + KS - 1;
  constexpr int NP2 = NPX / 2;
  __shared__ float lin[TILE + WIN];
  const int t = blockIdx.x, b = blockIdx.y, B = gridDim.y;

  for (int i = threadIdx.x; i < TILE + WIN; i += 512) lin[i] = 0.f;
  __syncthreads();
  const float* src = S + ((long)t * B + b) * (CIN * HW * HW);
  for (int i = threadIdx.x; i < CIN * HW * HW; i += 512) {
    int ci = i / (HW * HW), r = i % (HW * HW);
    int iy = r / HW, ix = r % HW;
    lin[ci * PH * RS + (iy + PAD) * RS + ix + PAD] = src[i];
  }
  __syncthreads();

  const int lane = threadIdx.x & 63;
  const int g = __builtin_amdgcn_readfirstlane(threadIdx.x >> 6);  // 0..7
  const int co0 = g * NCO;
  const float* wb = Wt + (long)g * (CIN * KS * KS * NCO);

  for (int it = 0; it < NITER; ++it) {
    int slot = lane + 64 * it;
    bool act = slot < SLOTS;
    int ss = act ? slot : 0;
    int y = ss / XG, x0 = (ss % XG) * NPX;
    const float* base = lin + y * RS + x0;
    v2f acc[NCO][NP2];
#pragma unroll
    for (int j = 0; j < NCO; ++j)
#pragma unroll
      for (int p = 0; p < NP2; ++p) acc[j][p] = (v2f)(0.f);

    for (int ci = 0; ci < CIN; ++ci) {
      const float* bp = base + ci * (PH * RS);
      const float* wc = wb + ci * (KS * KS * NCO);
#pragma unroll
      for (int dy = 0; dy < KS; ++dy) {
        float win[WIN];
#pragma unroll
        for (int k = 0; k < WIN; ++k) win[k] = bp[dy * RS + k];
#pragma unroll
        for (int dx = 0; dx < KS; ++dx) {
          float wv[NCO];
#pragma unroll
          for (int j = 0; j < NCO; ++j)
            wv[j] = wc[(dy * KS + dx) * NCO + j];
#pragma unroll
          for (int p = 0; p < NP2; ++p) {
            v2f xp;
            xp.x = win[2 * p + dx];
            xp.y = win[2 * p + 1 + dx];
#pragma unroll
            for (int j = 0; j < NCO; ++j)
              acc[j][p] += xp * wv[j];
          }
        }
      }
    }
    if (act) {
      float* up = U + (((long)t * B + b) * CO + co0) * (HW * HW) + y * HW + x0;
#pragma unroll
      for (int j = 0; j < NCO; ++j)
#pragma unroll
        for (int p = 0; p < NP2; ++p) {
          if (x0 + 2 * p < HW) up[j * (HW * HW) + 2 * p] = acc[j][p].x;
          if (x0 + 2 * p + 1 < HW) up[j * (HW * HW) + 2 * p + 1] = acc[j][p].y;
        }
    }
  }
}

// ---------------- fused psp->pool(x11)->psp, 4 lanes/neuron, 4-deep prefetch ----------------
template <int C, int HIN, int HOUT>
__global__ __launch_bounds__(128) void ppp4_tm(const float* __restrict__ U,
                                               float* __restrict__ out, int B) {
  const int NOUT = B * C * HOUT * HOUT;
  const long SIN = (long)B * C * HIN * HIN;
  int id = blockIdx.x * 128 + threadIdx.x;
  int sub = id & 3, m = id >> 2;
  bool active = m < NOUT;
  int mm = active ? m : 0;
  int x2 = mm % HOUT;
  int y2 = (mm / HOUT) % HOUT;
  int c = (mm / (HOUT * HOUT)) % C;
  int b = mm / (C * HOUT * HOUT);
  int iy = 2 * y2 + (sub >> 1), ix = 2 * x2 + (sub & 1);
  bool valid = active && iy < HIN && ix < HIN;
  const float* base = U + ((long)(b * C + c) * HIN + iy) * HIN + ix;
  bool writer = active && (sub == 0);
  float* op = out + mm;
  IIR si, so;
  float pr0 = valid ? base[0] : 0.f;
  float pr1 = valid ? base[SIN] : 0.f;
  float pr2 = valid ? base[2 * SIN] : 0.f;
  float pr3 = valid ? base[3 * SIN] : 0.f;
  for (int tb = 0; tb < TT; tb += 4) {
    float a0 = pr0, a1 = pr1, a2 = pr2, a3 = pr3;
    const float* nb = base + (long)(tb + 4) * SIN;  // last iter overreads into ws
    pr0 = valid ? nb[0] : 0.f;
    pr1 = valid ? nb[SIN] : 0.f;
    pr2 = valid ? nb[2 * SIN] : 0.f;
    pr3 = valid ? nb[3 * SIN] : 0.f;
    {
      float s = si.step(a0);
      float v = s + __shfl_xor(s, 1); v += __shfl_xor(v, 2);
      float o = so.step(11.0f * v);
      if (writer) op[(long)tb * NOUT] = o;
    }
    {
      float s = si.step(a1);
      float v = s + __shfl_xor(s, 1); v += __shfl_xor(v, 2);
      float o = so.step(11.0f * v);
      if (writer) op[(long)(tb + 1) * NOUT] = o;
    }
    {
      float s = si.step(a2);
      float v = s + __shfl_xor(s, 1); v += __shfl_xor(v, 2);
      float o = so.step(11.0f * v);
      if (writer) op[(long)(tb + 2) * NOUT] = o;
    }
    {
      float s = si.step(a3);
      float v = s + __shfl_xor(s, 1); v += __shfl_xor(v, 2);
      float o = so.step(11.0f * v);
      if (writer) op[(long)(tb + 3) * NOUT] = o;
    }
  }
}

// ---------------- dense7k: split-k x8 GEMM, P[kz][row][o] partials ----------------
__global__ __launch_bounds__(256) void dense7k(const float* __restrict__ S,
                                               const float* __restrict__ Wt,
                                               float* __restrict__ P) {
  const int r0 = blockIdx.x * 16 + (threadIdx.x >> 6) * 4;
  const int kz = blockIdx.y;
  const int lane = threadIdx.x & 63;
  const float* s0 = S + (long)r0 * 2400;
  const float* s1 = s0 + 2400;
  const float* s2 = s0 + 4800;
  const float* s3 = s0 + 7200;
  const float* wp = Wt + lane * 4;
  v2f aA[4], aB[4];
#pragma unroll
  for (int o = 0; o < 4; ++o) { aA[o] = (v2f)(0.f); aB[o] = (v2f)(0.f); }
  const int k0 = kz * 300, k1 = k0 + 300;
  for (int k = k0; k < k1; k += 4) {
    float4 a0 = *(const float4*)(s0 + k);
    float4 a1 = *(const float4*)(s1 + k);
    float4 a2 = *(const float4*)(s2 + k);
    float4 a3 = *(const float4*)(s3 + k);
#define DSTEP(KK, AX)                                                        \
    {                                                                        \
      float4 w = *(const float4*)(wp + (long)(k + KK) * 256);                \
      v2f pA, pB;                                                            \
      pA.x = a0.AX; pA.y = a1.AX; pB.x = a2.AX; pB.y = a3.AX;                \
      aA[0] += pA * w.x; aA[1] += pA * w.y; aA[2] += pA * w.z; aA[3] += pA * w.w; \
      aB[0] += pB * w.x; aB[1] += pB * w.y; aB[2] += pB * w.z; aB[3] += pB * w.w; \
    }
    DSTEP(0, x) DSTEP(1, y) DSTEP(2, z) DSTEP(3, w)
#undef DSTEP
  }
  float* p = P + (long)kz * 307200 + (long)r0 * 256 + lane * 4;
#pragma unroll
  for (int o = 0; o < 4; ++o) p[o] = aA[o].x;
#pragma unroll
  for (int o = 0; o < 4; ++o) p[256 + o] = aA[o].y;
#pragma unroll
  for (int o = 0; o < 4; ++o) p[512 + o] = aB[o].x;
#pragma unroll
  for (int o = 0; o < 4; ++o) p[768 + o] = aB[o].y;
}

// ---------------- reduce8: U7 = sum of 8 partials (float4, ascending kz) ----------------
__global__ __launch_bounds__(256) void reduce8(const float* __restrict__ P,
                                               float* __restrict__ U7) {
  int i = blockIdx.x * 256 + threadIdx.x;  // over 76800 float4s
  if (i >= 76800) return;
  const float4* p = (const float4*)P;
  float4 a = p[i];
#pragma unroll
  for (int kz = 1; kz < 8; ++kz) {
    float4 b = p[(long)kz * 76800 + i];
    a.x += b.x; a.y += b.y; a.z += b.z; a.w += b.w;
  }
  ((float4*)U7)[i] = a;
}

// ---------------- psp7: psp+spike over U7, 4-deep prefetch ----------------
__global__ __launch_bounds__(128) void psp7(const float* __restrict__ U7,
                                            float* __restrict__ out) {
  int n = blockIdx.x * 128 + threadIdx.x;  // 0..1023
  IIR st;
  float pr0 = U7[n], pr1 = U7[1024 + n], pr2 = U7[2048 + n], pr3 = U7[3072 + n];
  for (int tb = 0; tb < TT; tb += 4) {
    float a0 = pr0, a1 = pr1, a2 = pr2, a3 = pr3;
    const float* nb = U7 + (long)(tb + 4) * 1024 + n;  // overreads into ws at end
    pr0 = nb[0]; pr1 = nb[1024]; pr2 = nb[2048]; pr3 = nb[3072];
    out[(long)tb * 1024 + n] = st.step(a0);
    out[(long)(tb + 1) * 1024 + n] = st.step(a1);
    out[(long)(tb + 2) * 1024 + n] = st.step(a2);
    out[(long)(tb + 3) * 1024 + n] = st.step(a3);
  }
}

// ---------------- dense8 ----------------
__global__ __launch_bounds__(256) void dense8(const float* __restrict__ S,
                                              const float* __restrict__ W,
                                              float* __restrict__ U) {
  int id = blockIdx.x * 256 + threadIdx.x;
  if (id >= 12000) return;
  int o = id % 10, row = id / 10;
  const float* sr = S + (long)row * 256;
  const float* wr = W + o * 256;
  float acc = 0.f;
  for (int k = 0; k < 256; k += 4) {
    float4 a = *(const float4*)(sr + k);
    float4 w = *(const float4*)(wr + k);
    acc += a.x * w.x; acc += a.y * w.y; acc += a.z * w.z; acc += a.w * w.w;
  }
  U[id] = acc;
}

// ---------------- final psp+spike + transpose to (B,10,T), prefetched ----------------
__global__ void psp8_out(const float* __restrict__ U, float* __restrict__ out) {
  int n = threadIdx.x;
  bool act = n < 40;
  int nn = act ? n : 0;
  IIR st;
  float pr0 = U[nn], pr1 = U[40 + nn], pr2 = U[80 + nn], pr3 = U[120 + nn];
  for (int tb = 0; tb < TT; tb += 4) {
    float a0 = pr0, a1 = pr1, a2 = pr2, a3 = pr3;
    const float* nb = U + (long)(tb + 4) * 40 + nn;  // overreads into ws at end
    pr0 = nb[0]; pr1 = nb[40]; pr2 = nb[80]; pr3 = nb[120];
    float o0 = st.step(a0), o1 = st.step(a1), o2 = st.step(a2), o3 = st.step(a3);
    if (act) {
      out[nn * TT + tb] = o0;
      out[nn * TT + tb + 1] = o1;
      out[nn * TT + tb + 2] = o2;
      out[nn * TT + tb + 3] = o3;
    }
  }
}

extern "C" void kernel_launch(void* const* d_in, const int* in_sizes, int n_in,
                              void* d_out, int out_size, void* d_ws, size_t ws_size,
                              hipStream_t stream) {
  const float* s_in = (const float*)d_in[0];
  const float* Wc1  = (const float*)d_in[1];
  const float* Wc2  = (const float*)d_in[2];
  const float* Wc3  = (const float*)d_in[3];
  const float* Wd4a = (const float*)d_in[4];
  const float* Wd4b = (const float*)d_in[5];

  float* Buf1 = (float*)d_ws;            // 33,292,800 floats (U1/U3/U5)
  float* Buf2 = Buf1 + 33292800;
  float* s2   = Buf2;                    //  8,323,200
  float* s4   = Buf2 + 8323200;          //  4,665,600
  float* Wt4a = Buf2 + 12988800;         //    614,400
  float* T0   = Buf2 + 13910400;         //  2,774,400
  float* Wt1  = Buf2 + 16684800;         //      1,200
  float* Wt2  = Buf2 + 16686000;         //     10,368
  float* Wt3  = Buf2 + 16696368;         //     41,472
  float* s7   = Buf2 + 16737840;         //    307,200
  float* P7   = Buf2 + 17045040;         //  2,457,600 (8 x 307,200 partials)
  float* U7   = Buf2 + 19502640;         //    307,200
  float* s6   = Buf2;                    //  2,880,000 (s2 region, dead by L6)
  float* U8   = Buf1;                    //     12,000 (Buf1 dead by L8)

  // prep: input -> time-major; Wd4a -> [k][o]; conv weights -> [g][ci][k][NCO]
  transpose_rc<<<dim3(5, 145), 256, 0, stream>>>(s_in, T0, 9248, 300);
  transpose_rc<<<dim3(38, 4), 256, 0, stream>>>(Wd4a, Wt4a, 256, 2400);
  prep_w<<<208, 256, 0, stream>>>(Wc1, Wc2, Wc3, Wt1, Wt2, Wt3);

  // L1: conv 2->24 k5 p2 (8 waves x NCO=3, NPX=4, RS=39, NITER=5) -> 1200 blocks
  conv_tm8<2, 34, 5, 2, 24, 3, 4, 39, 5><<<dim3(300, 4), 512, 0, stream>>>(T0, Wt1, Buf1);
  // L1-psp + pool 34->17 + psp -> s2
  ppp4_tm<24, 34, 17><<<867, 128, 0, stream>>>(Buf1, s2, 4);
  // L3: conv 24->48 k3 p1 (8 waves x NCO=6, NPX=6, RS=19, NITER=1) -> 1200 blocks
  conv_tm8<24, 17, 3, 1, 48, 6, 6, 19, 1><<<dim3(300, 4), 512, 0, stream>>>(s2, Wt2, Buf1);
  // L3-psp + pool 17->9 + psp -> s4
  ppp4_tm<48, 17, 9><<<486, 128, 0, stream>>>(Buf1, s4, 4);
  // L5: conv 48->96 k3 p1 (8 waves x NCO=12, NPX=2, RS=13, NITER=1) -> 1200 blocks
  conv_tm8<48, 9, 3, 1, 96, 12, 2, 13, 1><<<dim3(300, 4), 512, 0, stream>>>(s4, Wt3, Buf1);
  // L5-psp + pool 9->5 + psp -> s6
  ppp4_tm<96, 9, 5><<<300, 128, 0, stream>>>(Buf1, s6, 4);
  // L7: dense 2400->256 split-k x8 ; fold partials ; psp -> s7
  dense7k<<<dim3(75, 8), 256, 0, stream>>>(s6, Wt4a, P7);
  reduce8<<<300, 256, 0, stream>>>(P7, U7);
  psp7<<<8, 128, 0, stream>>>(U7, s7);
  // L8: dense 256->10 ; psp + output transpose
  dense8<<<47, 256, 0, stream>>>(s7, Wd4b, U8);
  psp8_out<<<1, 64, 0, stream>>>(U8, (float*)d_out);
}

// Round 5
// 682.494 us; speedup vs baseline: 1.1511x; 1.0277x over previous
//
#include <hip/hip_runtime.h>

// SLAYER SNN forward, round 20 = round 19 resubmitted verbatim (round-19
// bench died on container acquisition, not on the kernel; static audit found
// no hang/OOB/alignment/capture hazards).
//  - conv5_mfma: L5 (48->96, 9x9, k3) as 3-plane bf16 GEMM, M=96 N=81 K=432
//    (14 K-chunks of 32, zero-padded). Activations are spikes (exactly 0/1,
//    exact in bf16); weights split exactly w = w0+w1+w2 into 3 bf16 planes
//    (prep_w5), accumulated in fp32 MFMA -> ulp-level reorder-class error.
//  - Both A and B fragments are built with the SAME k<->(group,elem)
//    bijection (k = kc*32 + (lane>>4)*8 + e), so any hardware k-slot
//    permutation cancels (A/B slot pairing is symmetric). C/D layout per
//    verified mapping: col=lane&15, row=(lane>>4)*4+reg.
//  - A planes staged per (m-tile, plane) into 14.3KB LDS (waves share;
//    avoids 6x redundant L1 traffic). B frags (56 VGPR) built once per wave
//    from the LDS-staged input tile via a k->offset table.
//  - Wm5 lives in T0's region (dead after L1 conv); prep_w5 launches after
//    the L1 conv. L1/L3 convs unchanged (r18 8-wave blocks).
// All fp32 elsewhere; IIR op ordering bit-matches the reference scan.

#define TT 300

#define A1 0.9048374180359595f   // exp(-1/10)
#define C1 0.2718281828459045f   // e/10
#define A2 0.36787944117144233f  // exp(-1)
#define C2 2.718281828459045f    // e
#define KREF (20.0f * C2)
#define THETA_F 10.0f

typedef float v2f __attribute__((ext_vector_type(2)));
typedef float f32x4 __attribute__((ext_vector_type(4)));
typedef short bf16x8 __attribute__((ext_vector_type(8)));

struct IIR {
  float p1, q1, p2, q2;
  __device__ IIR() : p1(0.f), q1(0.f), p2(0.f), q2(0.f) {}
  __device__ inline float step(float xin) {
    q1 = A1 * q1 + A1 * p1;
    float y = C1 * q1;
    p1 = A1 * p1 + xin;
    q2 = A2 * q2 + A2 * p2;
    float u = y - KREF * q2;
    float s = (u >= THETA_F) ? 1.0f : 0.0f;
    p2 = A2 * p2 + s;
    return s;
  }
};

// ---------------- generic tiled transpose: in[R][C] -> out[C][R] ----------------
__global__ __launch_bounds__(256) void transpose_rc(const float* __restrict__ in,
                                                    float* __restrict__ out,
                                                    int R, int C) {
  __shared__ float tile[64][65];
  int c0 = blockIdx.x * 64, r0 = blockIdx.y * 64;
  int tx = threadIdx.x & 63, ty = threadIdx.x >> 6;
  for (int i = ty; i < 64; i += 4) {
    int r = r0 + i, c = c0 + tx;
    if (r < R && c < C) tile[i][tx] = in[(long)r * C + c];
  }
  __syncthreads();
  for (int i = ty; i < 64; i += 4) {
    int c = c0 + i, r = r0 + tx;
    if (c < C && r < R) out[(long)c * R + r] = tile[tx][i];
  }
}

// ---------------- conv-weight relayout, one launch ----------------
// Wc[co][ci][ky][kx] -> Wg[g][ci][ky*kx][NCO], co = g*NCO + j.
// NCO per layer: L1=3, L3=6 (8 groups each -> one group per wave).
__global__ __launch_bounds__(256) void prep_w(const float* __restrict__ Wc1,
                                              const float* __restrict__ Wc2,
                                              const float* __restrict__ Wc3,
                                              float* __restrict__ Wg1,
                                              float* __restrict__ Wg2,
                                              float* __restrict__ Wg3) {
  int i = blockIdx.x * 256 + threadIdx.x;
  if (i < 1200) {  // L1: CIN*KS*KS = 50, NCO = 3
    int co = i / 50, rem = i % 50;
    int g = co / 3, j = co % 3;
    Wg1[(g * 50 + rem) * 3 + j] = Wc1[i];
    return;
  }
  i -= 1200;
  if (i < 10368) {  // L3: CIN*KS*KS = 216, NCO = 6
    int co = i / 216, rem = i % 216;
    int g = co / 6, j = co % 6;
    Wg2[(g * 216 + rem) * 6 + j] = Wc2[i];
    return;
  }
  i -= 10368;
  if (i < 41472) {  // L5 legacy layout (unused by MFMA path; kept harmless)
    int co = i / 432, rem = i % 432;
    int g = co / 12, j = co % 12;
    Wg3[(g * 432 + rem) * 12 + j] = Wc3[i];
  }
}

// ---------------- prep_w5: 3-plane exact bf16 split of Wc3, fragment-major ----
// Wm[p][m][kc][lane][e] bf16 (ushort), p<3, m<6, kc<14, lane<64, e<8.
// co = m*16 + (lane&15); k = kc*32 + (lane>>4)*8 + e; k>=432 -> 0.
__device__ inline unsigned rne_bf16_bits(float f) {
  unsigned u = __float_as_uint(f);
  return (u + 0x7FFFu + ((u >> 16) & 1u)) >> 16;
}
__global__ __launch_bounds__(256) void prep_w5(const float* __restrict__ Wc3,
                                               ushort* __restrict__ Wm) {
  int i = blockIdx.x * 256 + threadIdx.x;  // over 6*14*64*8 = 43008
  if (i >= 43008) return;
  int e = i & 7, l = (i >> 3) & 63;
  int rest = i >> 9;           // m*14 + kc
  int kc = rest % 14, m = rest / 14;
  int co = m * 16 + (l & 15);
  int k = kc * 32 + (l >> 4) * 8 + e;
  float w = 0.f;
  if (k < 432) {
    int ci = k / 9, r = k % 9, dy = r / 3, dx = r % 3;
    w = Wc3[((co * 48 + ci) * 3 + dy) * 3 + dx];
  }
  unsigned b0 = rne_bf16_bits(w);
  float f0 = __uint_as_float(b0 << 16);
  float d1 = w - f0;
  unsigned b1 = rne_bf16_bits(d1);
  float f1 = __uint_as_float(b1 << 16);
  float d2 = d1 - f1;
  unsigned b2 = rne_bf16_bits(d2);
  Wm[i] = (ushort)b0;
  Wm[43008 + i] = (ushort)b1;
  Wm[2 * 43008 + i] = (ushort)b2;
}

// ---------------- conv5_mfma: L5 48->96 9x9 k3 p1 via bf16 MFMA ----------------
// S: [T][B][48][9][9] (spikes, exactly 0/1), Wm: fragment-major 3-plane bf16,
// U: [T][B][96][81]. 6 waves/block; wave = n-tile (16 px); B frags in 56 VGPR;
// A staged per (m,plane) in LDS. acc order: m { p { kc } } -> fp32 reorder only.
__global__ __launch_bounds__(384) void conv5_mfma(const float* __restrict__ S,
                                                  const ushort* __restrict__ Wm,
                                                  float* __restrict__ U) {
  constexpr int CIN = 48, HW = 9, PH = 11, RS = 13;
  constexpr int TILE = CIN * PH * RS;  // 6864
  __shared__ float lin[TILE];
  __shared__ int koff[448];
  __shared__ uint4 alds[896];          // one (m,plane): 14*64 frags * 16B
  const int t = blockIdx.x, b = blockIdx.y, B = gridDim.y;
  const int tid = threadIdx.x;

  for (int i = tid; i < TILE; i += 384) lin[i] = 0.f;
  for (int k = tid; k < 448; k += 384) {
    int ci = k / 9, r = k % 9, dy = r / 3, dx = r % 3;
    koff[k] = (k < 432) ? (ci * PH * RS + dy * RS + dx) : 0;
  }
  __syncthreads();
  const float* src = S + ((long)t * B + b) * (CIN * HW * HW);
  for (int i = tid; i < CIN * HW * HW; i += 384) {
    int ci = i / 81, r = i % 81, iy = r / 9, ix = r % 9;
    lin[ci * PH * RS + (iy + 1) * RS + ix + 1] = src[i];
  }
  __syncthreads();

  const int lane = tid & 63;
  const int wv = tid >> 6;        // wave id = n-tile 0..5
  const int g = lane >> 4;        // k-group
  const int col = lane & 15;
  int px = wv * 16 + col;
  bool vpx = px < 81;
  int ppx = vpx ? px : 0;
  int y = ppx / 9, x = ppx % 9;
  const int pxbase = y * RS + x;  // + koff[k] = ci*PH*RS + (y+dy)*RS + (x+dx)

  // Build B fragments: bf[kc][e] = spike at k = kc*32 + g*8 + e (0 for k>=432)
  bf16x8 bf[14];
#pragma unroll
  for (int kc = 0; kc < 14; ++kc) {
    bf16x8 v;
#pragma unroll
    for (int e = 0; e < 8; ++e) {
      int k = kc * 32 + g * 8 + e;
      float val = (k < 432) ? lin[pxbase + koff[k]] : 0.f;
      v[e] = (short)(__float_as_uint(val) >> 16);  // exact for 0/1
    }
    bf[kc] = v;
  }

  // MFMA over 6 m-tiles x 3 planes, A staged per (m,p) in LDS
  for (int m = 0; m < 6; ++m) {
    f32x4 acc = {0.f, 0.f, 0.f, 0.f};
    for (int p = 0; p < 3; ++p) {
      __syncthreads();  // prior round's alds reads complete
      const ushort* ws = Wm + (long)p * 43008 + m * 7168;
      for (int i = tid; i < 896; i += 384)
        alds[i] = *(const uint4*)(ws + i * 8);
      __syncthreads();
#pragma unroll
      for (int kc = 0; kc < 14; ++kc) {
        bf16x8 a = *(const bf16x8*)(alds + kc * 64 + lane);
        acc = __builtin_amdgcn_mfma_f32_16x16x32_bf16(a, bf[kc], acc, 0, 0, 0);
      }
    }
    if (vpx) {
      // D: col = lane&15 = px, row = g*4 + r = co within m-tile
      float* up = U + (((long)t * B + b) * 96 + m * 16 + g * 4) * 81 + px;
      up[0] = acc[0];
      up[81] = acc[1];
      up[162] = acc[2];
      up[243] = acc[3];
    }
  }
}

// ---------------- per-timestep conv, time-major, 8 waves/block (L1/L3) --------
template <int CIN, int HW, int KS, int PAD, int CO, int NCO, int NPX, int RS, int NITER>
__global__ __launch_bounds__(512) void conv_tm8(const float* __restrict__ S,
                                                const float* __restrict__ Wt,
                                                float* __restrict__ U) {
  constexpr int PH = HW + 2 * PAD;
  constexpr int TILE = CIN * PH * RS;
  constexpr int XG = (HW + NPX - 1) / NPX;
  constexpr int SLOTS = HW * XG;
  constexpr int WIN = NPX + KS - 1;
  constexpr int NP2 = NPX / 2;
  __shared__ float lin[TILE + WIN];
  const int t = blockIdx.x, b = blockIdx.y, B = gridDim.y;

  for (int i = threadIdx.x; i < TILE + WIN; i += 512) lin[i] = 0.f;
  __syncthreads();
  const float* src = S + ((long)t * B + b) * (CIN * HW * HW);
  for (int i = threadIdx.x; i < CIN * HW * HW; i += 512) {
    int ci = i / (HW * HW), r = i % (HW * HW);
    int iy = r / HW, ix = r % HW;
    lin[ci * PH * RS + (iy + PAD) * RS + ix + PAD] = src[i];
  }
  __syncthreads();

  const int lane = threadIdx.x & 63;
  const int g = __builtin_amdgcn_readfirstlane(threadIdx.x >> 6);  // 0..7
  const int co0 = g * NCO;
  const float* wb = Wt + (long)g * (CIN * KS * KS * NCO);

  for (int it = 0; it < NITER; ++it) {
    int slot = lane + 64 * it;
    bool act = slot < SLOTS;
    int ss = act ? slot : 0;
    int y = ss / XG, x0 = (ss % XG) * NPX;
    const float* base = lin + y * RS + x0;
    v2f acc[NCO][NP2];
#pragma unroll
    for (int j = 0; j < NCO; ++j)
#pragma unroll
      for (int p = 0; p < NP2; ++p) acc[j][p] = (v2f)(0.f);

    for (int ci = 0; ci < CIN; ++ci) {
      const float* bp = base + ci * (PH * RS);
      const float* wc = wb + ci * (KS * KS * NCO);
#pragma unroll
      for (int dy = 0; dy < KS; ++dy) {
        float win[WIN];
#pragma unroll
        for (int k = 0; k < WIN; ++k) win[k] = bp[dy * RS + k];
#pragma unroll
        for (int dx = 0; dx < KS; ++dx) {
          float wv[NCO];
#pragma unroll
          for (int j = 0; j < NCO; ++j)
            wv[j] = wc[(dy * KS + dx) * NCO + j];
#pragma unroll
          for (int p = 0; p < NP2; ++p) {
            v2f xp;
            xp.x = win[2 * p + dx];
            xp.y = win[2 * p + 1 + dx];
#pragma unroll
            for (int j = 0; j < NCO; ++j)
              acc[j][p] += xp * wv[j];
          }
        }
      }
    }
    if (act) {
      float* up = U + (((long)t * B + b) * CO + co0) * (HW * HW) + y * HW + x0;
#pragma unroll
      for (int j = 0; j < NCO; ++j)
#pragma unroll
        for (int p = 0; p < NP2; ++p) {
          if (x0 + 2 * p < HW) up[j * (HW * HW) + 2 * p] = acc[j][p].x;
          if (x0 + 2 * p + 1 < HW) up[j * (HW * HW) + 2 * p + 1] = acc[j][p].y;
        }
    }
  }
}

// ---------------- fused psp->pool(x11)->psp, 4 lanes/neuron, 4-deep prefetch ----------------
template <int C, int HIN, int HOUT>
__global__ __launch_bounds__(128) void ppp4_tm(const float* __restrict__ U,
                                               float* __restrict__ out, int B) {
  const int NOUT = B * C * HOUT * HOUT;
  const long SIN = (long)B * C * HIN * HIN;
  int id = blockIdx.x * 128 + threadIdx.x;
  int sub = id & 3, m = id >> 2;
  bool active = m < NOUT;
  int mm = active ? m : 0;
  int x2 = mm % HOUT;
  int y2 = (mm / HOUT) % HOUT;
  int c = (mm / (HOUT * HOUT)) % C;
  int b = mm / (C * HOUT * HOUT);
  int iy = 2 * y2 + (sub >> 1), ix = 2 * x2 + (sub & 1);
  bool valid = active && iy < HIN && ix < HIN;
  const float* base = U + ((long)(b * C + c) * HIN + iy) * HIN + ix;
  bool writer = active && (sub == 0);
  float* op = out + mm;
  IIR si, so;
  float pr0 = valid ? base[0] : 0.f;
  float pr1 = valid ? base[SIN] : 0.f;
  float pr2 = valid ? base[2 * SIN] : 0.f;
  float pr3 = valid ? base[3 * SIN] : 0.f;
  for (int tb = 0; tb < TT; tb += 4) {
    float a0 = pr0, a1 = pr1, a2 = pr2, a3 = pr3;
    const float* nb = base + (long)(tb + 4) * SIN;  // last iter overreads into ws
    pr0 = valid ? nb[0] : 0.f;
    pr1 = valid ? nb[SIN] : 0.f;
    pr2 = valid ? nb[2 * SIN] : 0.f;
    pr3 = valid ? nb[3 * SIN] : 0.f;
    {
      float s = si.step(a0);
      float v = s + __shfl_xor(s, 1); v += __shfl_xor(v, 2);
      float o = so.step(11.0f * v);
      if (writer) op[(long)tb * NOUT] = o;
    }
    {
      float s = si.step(a1);
      float v = s + __shfl_xor(s, 1); v += __shfl_xor(v, 2);
      float o = so.step(11.0f * v);
      if (writer) op[(long)(tb + 1) * NOUT] = o;
    }
    {
      float s = si.step(a2);
      float v = s + __shfl_xor(s, 1); v += __shfl_xor(v, 2);
      float o = so.step(11.0f * v);
      if (writer) op[(long)(tb + 2) * NOUT] = o;
    }
    {
      float s = si.step(a3);
      float v = s + __shfl_xor(s, 1); v += __shfl_xor(v, 2);
      float o = so.step(11.0f * v);
      if (writer) op[(long)(tb + 3) * NOUT] = o;
    }
  }
}

// ---------------- dense7k: split-k x8 GEMM, P[kz][row][o] partials ----------------
__global__ __launch_bounds__(256) void dense7k(const float* __restrict__ S,
                                               const float* __restrict__ Wt,
                                               float* __restrict__ P) {
  const int r0 = blockIdx.x * 16 + (threadIdx.x >> 6) * 4;
  const int kz = blockIdx.y;
  const int lane = threadIdx.x & 63;
  const float* s0 = S + (long)r0 * 2400;
  const float* s1 = s0 + 2400;
  const float* s2 = s0 + 4800;
  const float* s3 = s0 + 7200;
  const float* wp = Wt + lane * 4;
  v2f aA[4], aB[4];
#pragma unroll
  for (int o = 0; o < 4; ++o) { aA[o] = (v2f)(0.f); aB[o] = (v2f)(0.f); }
  const int k0 = kz * 300, k1 = k0 + 300;
  for (int k = k0; k < k1; k += 4) {
    float4 a0 = *(const float4*)(s0 + k);
    float4 a1 = *(const float4*)(s1 + k);
    float4 a2 = *(const float4*)(s2 + k);
    float4 a3 = *(const float4*)(s3 + k);
#define DSTEP(KK, AX)                                                        \
    {                                                                        \
      float4 w = *(const float4*)(wp + (long)(k + KK) * 256);                \
      v2f pA, pB;                                                            \
      pA.x = a0.AX; pA.y = a1.AX; pB.x = a2.AX; pB.y = a3.AX;                \
      aA[0] += pA * w.x; aA[1] += pA * w.y; aA[2] += pA * w.z; aA[3] += pA * w.w; \
      aB[0] += pB * w.x; aB[1] += pB * w.y; aB[2] += pB * w.z; aB[3] += pB * w.w; \
    }
    DSTEP(0, x) DSTEP(1, y) DSTEP(2, z) DSTEP(3, w)
#undef DSTEP
  }
  float* p = P + (long)kz * 307200 + (long)r0 * 256 + lane * 4;
#pragma unroll
  for (int o = 0; o < 4; ++o) p[o] = aA[o].x;
#pragma unroll
  for (int o = 0; o < 4; ++o) p[256 + o] = aA[o].y;
#pragma unroll
  for (int o = 0; o < 4; ++o) p[512 + o] = aB[o].x;
#pragma unroll
  for (int o = 0; o < 4; ++o) p[768 + o] = aB[o].y;
}

// ---------------- reduce8: U7 = sum of 8 partials (float4, ascending kz) ----------------
__global__ __launch_bounds__(256) void reduce8(const float* __restrict__ P,
                                               float* __restrict__ U7) {
  int i = blockIdx.x * 256 + threadIdx.x;  // over 76800 float4s
  if (i >= 76800) return;
  const float4* p = (const float4*)P;
  float4 a = p[i];
#pragma unroll
  for (int kz = 1; kz < 8; ++kz) {
    float4 b = p[(long)kz * 76800 + i];
    a.x += b.x; a.y += b.y; a.z += b.z; a.w += b.w;
  }
  ((float4*)U7)[i] = a;
}

// ---------------- psp7: psp+spike over U7, 4-deep prefetch ----------------
__global__ __launch_bounds__(128) void psp7(const float* __restrict__ U7,
                                            float* __restrict__ out) {
  int n = blockIdx.x * 128 + threadIdx.x;  // 0..1023
  IIR st;
  float pr0 = U7[n], pr1 = U7[1024 + n], pr2 = U7[2048 + n], pr3 = U7[3072 + n];
  for (int tb = 0; tb < TT; tb += 4) {
    float a0 = pr0, a1 = pr1, a2 = pr2, a3 = pr3;
    const float* nb = U7 + (long)(tb + 4) * 1024 + n;  // overreads into ws at end
    pr0 = nb[0]; pr1 = nb[1024]; pr2 = nb[2048]; pr3 = nb[3072];
    out[(long)tb * 1024 + n] = st.step(a0);
    out[(long)(tb + 1) * 1024 + n] = st.step(a1);
    out[(long)(tb + 2) * 1024 + n] = st.step(a2);
    out[(long)(tb + 3) * 1024 + n] = st.step(a3);
  }
}

// ---------------- dense8 ----------------
__global__ __launch_bounds__(256) void dense8(const float* __restrict__ S,
                                              const float* __restrict__ W,
                                              float* __restrict__ U) {
  int id = blockIdx.x * 256 + threadIdx.x;
  if (id >= 12000) return;
  int o = id % 10, row = id / 10;
  const float* sr = S + (long)row * 256;
  const float* wr = W + o * 256;
  float acc = 0.f;
  for (int k = 0; k < 256; k += 4) {
    float4 a = *(const float4*)(sr + k);
    float4 w = *(const float4*)(wr + k);
    acc += a.x * w.x; acc += a.y * w.y; acc += a.z * w.z; acc += a.w * w.w;
  }
  U[id] = acc;
}

// ---------------- final psp+spike + transpose to (B,10,T), prefetched ----------------
__global__ void psp8_out(const float* __restrict__ U, float* __restrict__ out) {
  int n = threadIdx.x;
  bool act = n < 40;
  int nn = act ? n : 0;
  IIR st;
  float pr0 = U[nn], pr1 = U[40 + nn], pr2 = U[80 + nn], pr3 = U[120 + nn];
  for (int tb = 0; tb < TT; tb += 4) {
    float a0 = pr0, a1 = pr1, a2 = pr2, a3 = pr3;
    const float* nb = U + (long)(tb + 4) * 40 + nn;  // overreads into ws at end
    pr0 = nb[0]; pr1 = nb[40]; pr2 = nb[80]; pr3 = nb[120];
    float o0 = st.step(a0), o1 = st.step(a1), o2 = st.step(a2), o3 = st.step(a3);
    if (act) {
      out[nn * TT + tb] = o0;
      out[nn * TT + tb + 1] = o1;
      out[nn * TT + tb + 2] = o2;
      out[nn * TT + tb + 3] = o3;
    }
  }
}

extern "C" void kernel_launch(void* const* d_in, const int* in_sizes, int n_in,
                              void* d_out, int out_size, void* d_ws, size_t ws_size,
                              hipStream_t stream) {
  const float* s_in = (const float*)d_in[0];
  const float* Wc1  = (const float*)d_in[1];
  const float* Wc2  = (const float*)d_in[2];
  const float* Wc3  = (const float*)d_in[3];
  const float* Wd4a = (const float*)d_in[4];
  const float* Wd4b = (const float*)d_in[5];

  float* Buf1 = (float*)d_ws;            // 33,292,800 floats (U1/U3/U5)
  float* Buf2 = Buf1 + 33292800;
  float* s2   = Buf2;                    //  8,323,200
  float* s4   = Buf2 + 8323200;          //  4,665,600
  float* Wt4a = Buf2 + 12988800;         //    614,400
  float* T0   = Buf2 + 13910400;         //  2,774,400 (dead after L1 conv)
  float* Wt1  = Buf2 + 16684800;         //      1,200
  float* Wt2  = Buf2 + 16686000;         //     10,368
  float* Wt3  = Buf2 + 16696368;         //     41,472
  float* s7   = Buf2 + 16737840;         //    307,200
  float* P7   = Buf2 + 17045040;         //  2,457,600 (8 x 307,200 partials)
  float* U7   = Buf2 + 19502640;         //    307,200
  float* s6   = Buf2;                    //  2,880,000 (s2 region, dead by L6)
  float* U8   = Buf1;                    //     12,000 (Buf1 dead by L8)
  ushort* Wm5 = (ushort*)T0;             //    129,024 ushorts in T0 region

  // prep: input -> time-major; Wd4a -> [k][o]; conv weights -> [g][ci][k][NCO]
  transpose_rc<<<dim3(5, 145), 256, 0, stream>>>(s_in, T0, 9248, 300);
  transpose_rc<<<dim3(38, 4), 256, 0, stream>>>(Wd4a, Wt4a, 256, 2400);
  prep_w<<<208, 256, 0, stream>>>(Wc1, Wc2, Wc3, Wt1, Wt2, Wt3);

  // L1: conv 2->24 k5 p2 (8 waves x NCO=3, NPX=4, RS=39, NITER=5) -> 1200 blocks
  conv_tm8<2, 34, 5, 2, 24, 3, 4, 39, 5><<<dim3(300, 4), 512, 0, stream>>>(T0, Wt1, Buf1);
  // T0 now dead -> build L5 MFMA weight planes into its region
  prep_w5<<<168, 256, 0, stream>>>(Wc3, Wm5);
  // L1-psp + pool 34->17 + psp -> s2
  ppp4_tm<24, 34, 17><<<867, 128, 0, stream>>>(Buf1, s2, 4);
  // L3: conv 24->48 k3 p1 (8 waves x NCO=6, NPX=6, RS=19, NITER=1) -> 1200 blocks
  conv_tm8<24, 17, 3, 1, 48, 6, 6, 19, 1><<<dim3(300, 4), 512, 0, stream>>>(s2, Wt2, Buf1);
  // L3-psp + pool 17->9 + psp -> s4
  ppp4_tm<48, 17, 9><<<486, 128, 0, stream>>>(Buf1, s4, 4);
  // L5: conv 48->96 k3 p1 via bf16 MFMA (6 waves, 3 planes) -> 1200 blocks
  conv5_mfma<<<dim3(300, 4), 384, 0, stream>>>(s4, Wm5, Buf1);
  // L5-psp + pool 9->5 + psp -> s6
  ppp4_tm<96, 9, 5><<<300, 128, 0, stream>>>(Buf1, s6, 4);
  // L7: dense 2400->256 split-k x8 ; fold partials ; psp -> s7
  dense7k<<<dim3(75, 8), 256, 0, stream>>>(s6, Wt4a, P7);
  reduce8<<<300, 256, 0, stream>>>(P7, U7);
  psp7<<<8, 128, 0, stream>>>(U7, s7);
  // L8: dense 256->10 ; psp + output transpose
  dense8<<<47, 256, 0, stream>>>(s7, Wd4b, U8);
  psp8_out<<<1, 64, 0, stream>>>(U8, (float*)d_out);
}